// Round 1
// baseline (692.088 us; speedup 1.0000x reference)
//
#include <hip/hip_runtime.h>
#include <math.h>

#define NUM_USERS 100000
#define NUM_ITEMS 50000
#define NN 150000               // total nodes
#define EE 1200000              // total directed edges (2 * E_DIR)
#define NB 586                  // ceil(NN/256) scan blocks
#define NNP (NB * 256)          // padded node count = 150016
#define G8_BLOCKS 4688          // ceil(NN*8/256) for 8-lane-per-node kernels

typedef unsigned short ushort_t;
typedef unsigned int uint_t;

__device__ __forceinline__ uint_t pack2(float lo, float hi) {   // 2x fp32 -> bf16x2 RNE
    uint_t a = __float_as_uint(lo);
    uint_t b = __float_as_uint(hi);
    a = (a + 0x7FFFu + ((a >> 16) & 1u)) >> 16;
    b = (b + 0x7FFFu + ((b >> 16) & 1u)) & 0xFFFF0000u;
    return a | b;
}
__device__ __forceinline__ float lo16(uint_t x) { return __uint_as_float(x << 16); }
__device__ __forceinline__ float hi16(uint_t x) { return __uint_as_float(x & 0xFFFF0000u); }

// ---- fused edge MLP + count/rank (ONE atomic per edge) ----------------------
// er[e] = {rank, ew_bits};  rank = counts[col[e]]++ (atomic return)
// v2: 4 edges/thread; atomics issued BEFORE the MLP so their return latency
//     hides under compute; W1 transposed in LDS so weight reads are
//     2x ds_read_b128 + 1x ds_read_b64 per hidden unit (24 LDS ops/edge
//     instead of 256).
__global__ void mlp_count_kernel(const float* __restrict__ feats,
                                 const float* __restrict__ w1,
                                 const float* __restrict__ b1,
                                 const float* __restrict__ w2,
                                 const float* __restrict__ b2,
                                 const int* __restrict__ col,
                                 int2* __restrict__ er,
                                 int* __restrict__ counts) {
    __shared__ float sw1t[256];      // transposed: sw1t[j*8+i] = w1[i][j]
    __shared__ float2 shb[32];       // {b1[j], w2[j]}
    __shared__ float sb2s;
    int t = threadIdx.x;
    sw1t[t] = w1[(t & 7) * 32 + (t >> 3)];
    if (t < 32) shb[t] = make_float2(b1[t], w2[t]);
    if (t == 0) sb2s = b2[0];

    int e0 = blockIdx.x * 1024 + t;
    int rk[4];
    bool v[4];
    float f[4][8];
#pragma unroll
    for (int q = 0; q < 4; ++q) {
        int e = e0 + q * 256;
        v[q] = (e < EE);
        if (v[q]) {
            int c = col[e];
            rk[q] = atomicAdd(&counts[c], 1);   // issue early; return used late
        }
    }
#pragma unroll
    for (int q = 0; q < 4; ++q) {
        int e = e0 + q * 256;
        int eL = (e < EE) ? e : (EE - 1);        // clamped load, predicated use
        const float4* fp = (const float4*)(feats + (size_t)eL * 8);
        float4 fa = fp[0], fb = fp[1];
        f[q][0] = fa.x; f[q][1] = fa.y; f[q][2] = fa.z; f[q][3] = fa.w;
        f[q][4] = fb.x; f[q][5] = fb.y; f[q][6] = fb.z; f[q][7] = fb.w;
    }
    __syncthreads();
    float acc[4] = {0.f, 0.f, 0.f, 0.f};
#pragma unroll
    for (int j = 0; j < 32; ++j) {
        float4 wa = *(const float4*)&sw1t[j * 8];
        float4 wb = *(const float4*)&sw1t[j * 8 + 4];
        float2 bw = shb[j];
#pragma unroll
        for (int q = 0; q < 4; ++q) {
            float h = bw.x;
            h = fmaf(f[q][0], wa.x, h);
            h = fmaf(f[q][1], wa.y, h);
            h = fmaf(f[q][2], wa.z, h);
            h = fmaf(f[q][3], wa.w, h);
            h = fmaf(f[q][4], wb.x, h);
            h = fmaf(f[q][5], wb.y, h);
            h = fmaf(f[q][6], wb.z, h);
            h = fmaf(f[q][7], wb.w, h);
            h = fmaxf(h, 0.f);
            acc[q] = fmaf(h, bw.y, acc[q]);
        }
    }
    float sb2v = sb2s;
#pragma unroll
    for (int q = 0; q < 4; ++q) {
        if (v[q]) {
            float s = acc[q] + sb2v;
            float w = 1.f / (1.f + expf(-s));
            er[e0 + q * 256] = make_int2(rk[q], __float_as_int(w));
        }
    }
}

// ---- scan step 1: per-block exclusive scan of counts; block totals ----------
__global__ void scan1_kernel(const int* __restrict__ counts,
                             int* __restrict__ offs,
                             int* __restrict__ partials) {
    int i = blockIdx.x * 256 + threadIdx.x;
    int lane = threadIdx.x & 63;
    int v = counts[i];                           // [NN,NNP) pre-zeroed
    int s = v;
#pragma unroll
    for (int off = 1; off < 64; off <<= 1) {
        int u = __shfl_up(s, off, 64);
        if (lane >= off) s += u;
    }
    __shared__ int wsum[4];
    if (lane == 63) wsum[threadIdx.x >> 6] = s;
    __syncthreads();
    int add = 0;
    for (int w = 0; w < (threadIdx.x >> 6); ++w) add += wsum[w];
    offs[i] = s - v + add;
    if (threadIdx.x == 255) partials[blockIdx.x] = s + add;
}

// ---- scan step 2+3 fused: every block scans partials in LDS, adds its base --
__global__ void scan23_kernel(int* __restrict__ offs,
                              const int* __restrict__ partials) {
    __shared__ int sp[768];                      // NB=586 padded to 768 = 256*3
    __shared__ int wsum[4];
    int t = threadIdx.x;
#pragma unroll
    for (int k = 0; k < 3; ++k) {
        int idx = t + k * 256;
        sp[idx] = (idx < NB) ? partials[idx] : 0;
    }
    __syncthreads();
    int v0 = sp[3 * t], v1 = sp[3 * t + 1], v2 = sp[3 * t + 2];
    int tot = v0 + v1 + v2;
    int lane = t & 63;
    int s = tot;
#pragma unroll
    for (int off = 1; off < 64; off <<= 1) {
        int u = __shfl_up(s, off, 64);
        if (lane >= off) s += u;
    }
    if (lane == 63) wsum[t >> 6] = s;
    __syncthreads();
    int add = 0;
    for (int w = 0; w < (t >> 6); ++w) add += wsum[w];
    int excl = s - tot + add;
    sp[3 * t]     = excl;
    sp[3 * t + 1] = excl + v0;
    sp[3 * t + 2] = excl + v0 + v1;
    __syncthreads();
    int base = sp[blockIdx.x];                   // exclusive prefix of totals
    int i = blockIdx.x * 256 + t;
    offs[i] = offs[i] + base;
}

// ---- atomic-free CSR fill: packed[offs[col]+rank] = {row, ew} ---------------
__global__ void fill_kernel(const int2* __restrict__ er,
                            const int* __restrict__ row,
                            const int* __restrict__ col,
                            const int* __restrict__ offs,
                            int2* __restrict__ packed) {
    int e = blockIdx.x * 256 + threadIdx.x;
    if (e >= EE) return;
    int2 p = er[e];
    int slot = offs[col[e]] + p.x;
    packed[slot] = make_int2(row[e], p.y);
}

// ---- gather core: 8 lanes per node, 16B loads; a0/a1 = cols 8c..8c+7 --------
__device__ __forceinline__ void gather_node8(const ushort_t* __restrict__ zin,
                                             const int2* __restrict__ packed,
                                             int beg, int end, unsigned c,
                                             float4& a0, float4& a1) {
    for (int base = beg; base < end; base += 8) {
        int m = end - base; if (m > 8) m = 8;
        int r = 0; float w = 0.f;
        if ((int)c < m) {
            int2 p = packed[base + (int)c];
            r = p.x; w = __int_as_float(p.y);
        }
        int rj[8]; float wj[8]; uint4 vj[8];
#pragma unroll
        for (int u = 0; u < 8; ++u) {
            int idx = (u < m) ? u : (m - 1);       // clamp: re-read last valid row
            rj[u] = __shfl(r, idx, 8);
            wj[u] = __shfl(w, u, 8);               // lanes >= m carry w=0
        }
#pragma unroll
        for (int u = 0; u < 8; ++u)
            vj[u] = *(const uint4*)(zin + (size_t)(uint_t)rj[u] * 64u + c * 8u);
#pragma unroll
        for (int u = 0; u < 8; ++u) {
            float ww = wj[u]; uint4 v = vj[u];
            a0.x = fmaf(ww, lo16(v.x), a0.x);
            a0.y = fmaf(ww, hi16(v.x), a0.y);
            a0.z = fmaf(ww, lo16(v.y), a0.z);
            a0.w = fmaf(ww, hi16(v.y), a0.w);
            a1.x = fmaf(ww, lo16(v.z), a1.x);
            a1.y = fmaf(ww, hi16(v.z), a1.y);
            a1.z = fmaf(ww, lo16(v.w), a1.z);
            a1.w = fmaf(ww, hi16(v.w), a1.w);
        }
    }
}

// ---- fused dinv + z0 (8 lanes per node) -------------------------------------
__global__ void dinv_init_kernel(const int2* __restrict__ packed,
                                 const int* __restrict__ offs,
                                 const float* __restrict__ user_w,
                                 const float* __restrict__ audio,
                                 const float* __restrict__ artist_w,
                                 const float* __restrict__ album_w,
                                 const int* __restrict__ artist_ids,
                                 const int* __restrict__ album_ids,
                                 float* __restrict__ dinv,
                                 ushort_t* __restrict__ z0) {
    unsigned t = blockIdx.x * 256u + threadIdx.x;
    unsigned node = t >> 3, c = t & 7u;
    if (node >= NN) return;
    int beg = offs[node], end = offs[node + 1];
    float ds = 0.f;
    for (int k = beg + (int)c; k < end; k += 8) ds += __int_as_float(packed[k].y);
    ds += __shfl_xor(ds, 1, 8);
    ds += __shfl_xor(ds, 2, 8);
    ds += __shfl_xor(ds, 4, 8);
    float d = (ds > 0.f) ? rsqrtf(ds) : 0.f;
    if (c == 0) dinv[node] = d;

    size_t ri = (size_t)node * 64u + c * 8u;
    float v[8];
    if (node < NUM_USERS) {
        float4 x0 = *(const float4*)(user_w + ri);
        float4 x1 = *(const float4*)(user_w + ri + 4);
        v[0]=x0.x; v[1]=x0.y; v[2]=x0.z; v[3]=x0.w;
        v[4]=x1.x; v[5]=x1.y; v[6]=x1.z; v[7]=x1.w;
    } else {
        unsigned j = node - NUM_USERS;
        unsigned aid = (unsigned)artist_ids[j], bid = (unsigned)album_ids[j];
        const float* ap = artist_w + (size_t)aid * 64u + c * 8u;
        const float* bp = album_w  + (size_t)bid * 64u + c * 8u;
        const float* up = audio    + (size_t)j   * 64u + c * 8u;
        float4 A0 = *(const float4*)ap, A1 = *(const float4*)(ap + 4);
        float4 B0 = *(const float4*)bp, B1 = *(const float4*)(bp + 4);
        float4 U0 = *(const float4*)up, U1 = *(const float4*)(up + 4);
        v[0] = fmaf(0.44f, A0.x + B0.x, 0.3f * U0.x);
        v[1] = fmaf(0.44f, A0.y + B0.y, 0.3f * U0.y);
        v[2] = fmaf(0.44f, A0.z + B0.z, 0.3f * U0.z);
        v[3] = fmaf(0.44f, A0.w + B0.w, 0.3f * U0.w);
        v[4] = fmaf(0.44f, A1.x + B1.x, 0.3f * U1.x);
        v[5] = fmaf(0.44f, A1.y + B1.y, 0.3f * U1.y);
        v[6] = fmaf(0.44f, A1.z + B1.z, 0.3f * U1.z);
        v[7] = fmaf(0.44f, A1.w + B1.w, 0.3f * U1.w);
    }
    float s = 0.f;
#pragma unroll
    for (int k = 0; k < 8; ++k) s = fmaf(v[k], v[k], s);
    s += __shfl_xor(s, 1, 8);
    s += __shfl_xor(s, 2, 8);
    s += __shfl_xor(s, 4, 8);
    float rn = rsqrtf(fmaxf(s, 1e-24f));          // == 1/max(||x||,1e-12)
    float scale = ((d > 0.f) ? d : 1.f) * rn;
    uint4 o;
    o.x = pack2(v[0] * scale, v[1] * scale);
    o.y = pack2(v[2] * scale, v[3] * scale);
    o.z = pack2(v[4] * scale, v[5] * scale);
    o.w = pack2(v[6] * scale, v[7] * scale);
    *(uint4*)(z0 + ri) = o;
}

// ---- SpMM layer in z-space: zout[n] = dinv_n^2 * sum ew * zin[row] ----------
__global__ void spmm_kernel(const ushort_t* __restrict__ zin,
                            const int2* __restrict__ packed,
                            const int* __restrict__ offs,
                            const float* __restrict__ dinv,
                            ushort_t* __restrict__ zout) {
    unsigned t = blockIdx.x * 256u + threadIdx.x;
    unsigned node = t >> 3, c = t & 7u;
    if (node >= NN) return;
    float4 a0 = make_float4(0,0,0,0), a1 = make_float4(0,0,0,0);
    gather_node8(zin, packed, offs[node], offs[node + 1], c, a0, a1);
    float d = dinv[node], dd = d * d;
    uint4 o;
    o.x = pack2(a0.x * dd, a0.y * dd);
    o.y = pack2(a0.z * dd, a0.w * dd);
    o.z = pack2(a1.x * dd, a1.y * dd);
    o.w = pack2(a1.z * dd, a1.w * dd);
    *(uint4*)(zout + (size_t)node * 64u + c * 8u) = o;
}

// ---- final layer fused with l2norm: out = l2norm((z0+z1+z2+z3)/4) -----------
__global__ void spmm_final_kernel(const ushort_t* __restrict__ z0,
                                  const ushort_t* __restrict__ z1,
                                  const ushort_t* __restrict__ z2,
                                  const int2* __restrict__ packed,
                                  const int* __restrict__ offs,
                                  const float* __restrict__ dinv,
                                  float* __restrict__ out) {
    unsigned t = blockIdx.x * 256u + threadIdx.x;
    unsigned node = t >> 3, c = t & 7u;
    if (node >= NN) return;
    float4 a0 = make_float4(0,0,0,0), a1 = make_float4(0,0,0,0);
    gather_node8(z2, packed, offs[node], offs[node + 1], c, a0, a1);
    float d = dinv[node], dd = d * d;
    size_t ri = (size_t)node * 64u + c * 8u;
    uint4 p0 = *(const uint4*)(z0 + ri);
    uint4 p1 = *(const uint4*)(z1 + ri);
    uint4 p2 = *(const uint4*)(z2 + ri);
    float v[8];
    v[0] = lo16(p0.x) + lo16(p1.x) + lo16(p2.x) + a0.x * dd;
    v[1] = hi16(p0.x) + hi16(p1.x) + hi16(p2.x) + a0.y * dd;
    v[2] = lo16(p0.y) + lo16(p1.y) + lo16(p2.y) + a0.z * dd;
    v[3] = hi16(p0.y) + hi16(p1.y) + hi16(p2.y) + a0.w * dd;
    v[4] = lo16(p0.z) + lo16(p1.z) + lo16(p2.z) + a1.x * dd;
    v[5] = hi16(p0.z) + hi16(p1.z) + hi16(p2.z) + a1.y * dd;
    v[6] = lo16(p0.w) + lo16(p1.w) + lo16(p2.w) + a1.z * dd;
    v[7] = hi16(p0.w) + hi16(p1.w) + hi16(p2.w) + a1.w * dd;
    float s = 0.f;
#pragma unroll
    for (int k = 0; k < 8; ++k) s = fmaf(v[k], v[k], s);
    s += __shfl_xor(s, 1, 8);
    s += __shfl_xor(s, 2, 8);
    s += __shfl_xor(s, 4, 8);
    float n = fmaxf(sqrtf(s) * 0.25f, 1e-12f);    // norm of acc/4, ref eps
    float inv = 0.25f / n;
    float4 o0 = make_float4(v[0]*inv, v[1]*inv, v[2]*inv, v[3]*inv);
    float4 o1 = make_float4(v[4]*inv, v[5]*inv, v[6]*inv, v[7]*inv);
    *(float4*)(out + ri)     = o0;
    *(float4*)(out + ri + 4) = o1;
    if (t == 0) out[(size_t)NN * 64u] = 0.f;      // align_loss
}

extern "C" void kernel_launch(void* const* d_in, const int* in_sizes, int n_in,
                              void* d_out, int out_size, void* d_ws, size_t ws_size,
                              hipStream_t stream) {
    const float* user_w     = (const float*)d_in[0];
    const float* audio      = (const float*)d_in[1];
    const float* artist_w   = (const float*)d_in[2];
    const float* album_w    = (const float*)d_in[3];
    const float* w1         = (const float*)d_in[4];
    const float* b1         = (const float*)d_in[5];
    const float* w2         = (const float*)d_in[6];
    const float* b2         = (const float*)d_in[7];
    const float* feats      = (const float*)d_in[8];
    const int*   row        = (const int*)d_in[9];
    const int*   col        = row + EE;
    const int*   artist_ids = (const int*)d_in[10];
    const int*   album_ids  = (const int*)d_in[11];
    float* out = (float*)d_out;

    // workspace (4B units): counts[NNP] offs[NNP+16] partials[1024]
    //                        er[EE int2] dinv[NN] packed[EE int2] z0..z2 ~79MB
    int*      counts   = (int*)d_ws;
    int*      offs     = counts + NNP;
    int*      partials = offs + NNP + 16;
    int2*     er       = (int2*)(partials + 1024);
    float*    dinv     = (float*)(er + EE);
    int2*     packed   = (int2*)(dinv + NN);
    ushort_t* z0       = (ushort_t*)(packed + EE);
    ushort_t* z1       = z0 + (size_t)NN * 64;
    ushort_t* z2       = z1 + (size_t)NN * 64;

    hipMemsetAsync(counts, 0, NNP * sizeof(int), stream);

    mlp_count_kernel<<<(EE + 1023) / 1024, 256, 0, stream>>>(feats, w1, b1, w2, b2,
                                                             col, er, counts);
    scan1_kernel<<<NB, 256, 0, stream>>>(counts, offs, partials);
    scan23_kernel<<<NB, 256, 0, stream>>>(offs, partials);
    fill_kernel<<<(EE + 255) / 256, 256, 0, stream>>>(er, row, col, offs, packed);
    dinv_init_kernel<<<G8_BLOCKS, 256, 0, stream>>>(packed, offs,
                                                    user_w, audio, artist_w, album_w,
                                                    artist_ids, album_ids, dinv, z0);
    spmm_kernel<<<G8_BLOCKS, 256, 0, stream>>>(z0, packed, offs, dinv, z1);
    spmm_kernel<<<G8_BLOCKS, 256, 0, stream>>>(z1, packed, offs, dinv, z2);
    spmm_final_kernel<<<G8_BLOCKS, 256, 0, stream>>>(z0, z1, z2, packed, offs,
                                                     dinv, out);
}

// Round 2
// 319.949 us; speedup vs baseline: 2.1631x; 2.1631x over previous
//
#include <hip/hip_runtime.h>
#include <math.h>

#define NUM_USERS 100000
#define NUM_ITEMS 50000
#define NN 150000               // total nodes
#define EE 1200000              // total directed edges (2 * E_DIR)
#define NB 586                  // ceil(NN/256) scan blocks
#define NNP (NB * 256)          // padded node count = 150016
#define G8_BLOCKS 4688          // ceil(NN*8/256) for 8-lane-per-node kernels

typedef unsigned short ushort_t;
typedef unsigned int uint_t;

__device__ __forceinline__ uint_t pack2(float lo, float hi) {   // 2x fp32 -> bf16x2 RNE
    uint_t a = __float_as_uint(lo);
    uint_t b = __float_as_uint(hi);
    a = (a + 0x7FFFu + ((a >> 16) & 1u)) >> 16;
    b = (b + 0x7FFFu + ((b >> 16) & 1u)) & 0xFFFF0000u;
    return a | b;
}
__device__ __forceinline__ float lo16(uint_t x) { return __uint_as_float(x << 16); }
__device__ __forceinline__ float hi16(uint_t x) { return __uint_as_float(x & 0xFFFF0000u); }

// ---- fused edge MLP + count/rank (ONE atomic per edge) ----------------------
// er[e] = {rank, ew_bits};  rank = counts[col[e]]++ (atomic return)
// v3: EXACT old structure (1 edge/thread, atomic in original late position —
//     the 4-edge batch of v2 exploded coherence traffic 15x). Only change:
//     W1 transposed in LDS so each hidden unit reads its 8 weights as
//     ds_read_b128 x2 + ds_read_b64 (96 LDS issues/thread vs ~320 b32).
__global__ void mlp_count_kernel(const float* __restrict__ feats,
                                 const float* __restrict__ w1,
                                 const float* __restrict__ b1,
                                 const float* __restrict__ w2,
                                 const float* __restrict__ b2,
                                 const int* __restrict__ col,
                                 int2* __restrict__ er,
                                 int* __restrict__ counts) {
    __shared__ float sw1t[256];      // transposed: sw1t[j*8+i] = w1[i][j]
    __shared__ float2 shb[32];       // {b1[j], w2[j]}
    __shared__ float sb2s;
    int t = threadIdx.x;
    sw1t[t] = w1[(t & 7) * 32 + (t >> 3)];
    if (t < 32) shb[t] = make_float2(b1[t], w2[t]);
    if (t == 0) sb2s = b2[0];
    __syncthreads();
    int e = blockIdx.x * 256 + t;
    if (e >= EE) return;
    int c = col[e];
    const float4* fp = (const float4*)(feats + (size_t)e * 8);
    float4 fa = fp[0], fb = fp[1];
    float f[8] = {fa.x, fa.y, fa.z, fa.w, fb.x, fb.y, fb.z, fb.w};
    float s = sb2s;
#pragma unroll
    for (int j = 0; j < 32; ++j) {
        float4 wa = *(const float4*)&sw1t[j * 8];
        float4 wb = *(const float4*)&sw1t[j * 8 + 4];
        float2 bw = shb[j];
        float h = bw.x;
        h = fmaf(f[0], wa.x, h);
        h = fmaf(f[1], wa.y, h);
        h = fmaf(f[2], wa.z, h);
        h = fmaf(f[3], wa.w, h);
        h = fmaf(f[4], wb.x, h);
        h = fmaf(f[5], wb.y, h);
        h = fmaf(f[6], wb.z, h);
        h = fmaf(f[7], wb.w, h);
        h = fmaxf(h, 0.f);
        s = fmaf(h, bw.y, s);
    }
    float w = 1.f / (1.f + expf(-s));
    int k = atomicAdd(&counts[c], 1);
    er[e] = make_int2(k, __float_as_int(w));
}

// ---- scan step 1: per-block exclusive scan of counts; block totals ----------
__global__ void scan1_kernel(const int* __restrict__ counts,
                             int* __restrict__ offs,
                             int* __restrict__ partials) {
    int i = blockIdx.x * 256 + threadIdx.x;
    int lane = threadIdx.x & 63;
    int v = counts[i];                           // [NN,NNP) pre-zeroed
    int s = v;
#pragma unroll
    for (int off = 1; off < 64; off <<= 1) {
        int u = __shfl_up(s, off, 64);
        if (lane >= off) s += u;
    }
    __shared__ int wsum[4];
    if (lane == 63) wsum[threadIdx.x >> 6] = s;
    __syncthreads();
    int add = 0;
    for (int w = 0; w < (threadIdx.x >> 6); ++w) add += wsum[w];
    offs[i] = s - v + add;
    if (threadIdx.x == 255) partials[blockIdx.x] = s + add;
}

// ---- scan step 2+3 fused: every block scans partials in LDS, adds its base --
__global__ void scan23_kernel(int* __restrict__ offs,
                              const int* __restrict__ partials) {
    __shared__ int sp[768];                      // NB=586 padded to 768 = 256*3
    __shared__ int wsum[4];
    int t = threadIdx.x;
#pragma unroll
    for (int k = 0; k < 3; ++k) {
        int idx = t + k * 256;
        sp[idx] = (idx < NB) ? partials[idx] : 0;
    }
    __syncthreads();
    int v0 = sp[3 * t], v1 = sp[3 * t + 1], v2 = sp[3 * t + 2];
    int tot = v0 + v1 + v2;
    int lane = t & 63;
    int s = tot;
#pragma unroll
    for (int off = 1; off < 64; off <<= 1) {
        int u = __shfl_up(s, off, 64);
        if (lane >= off) s += u;
    }
    if (lane == 63) wsum[t >> 6] = s;
    __syncthreads();
    int add = 0;
    for (int w = 0; w < (t >> 6); ++w) add += wsum[w];
    int excl = s - tot + add;
    sp[3 * t]     = excl;
    sp[3 * t + 1] = excl + v0;
    sp[3 * t + 2] = excl + v0 + v1;
    __syncthreads();
    int base = sp[blockIdx.x];                   // exclusive prefix of totals
    int i = blockIdx.x * 256 + t;
    offs[i] = offs[i] + base;
}

// ---- atomic-free CSR fill: packed[offs[col]+rank] = {row, ew} ---------------
__global__ void fill_kernel(const int2* __restrict__ er,
                            const int* __restrict__ row,
                            const int* __restrict__ col,
                            const int* __restrict__ offs,
                            int2* __restrict__ packed) {
    int e = blockIdx.x * 256 + threadIdx.x;
    if (e >= EE) return;
    int2 p = er[e];
    int slot = offs[col[e]] + p.x;
    packed[slot] = make_int2(row[e], p.y);
}

// ---- gather core: 8 lanes per node, 16B loads; a0/a1 = cols 8c..8c+7 --------
__device__ __forceinline__ void gather_node8(const ushort_t* __restrict__ zin,
                                             const int2* __restrict__ packed,
                                             int beg, int end, unsigned c,
                                             float4& a0, float4& a1) {
    for (int base = beg; base < end; base += 8) {
        int m = end - base; if (m > 8) m = 8;
        int r = 0; float w = 0.f;
        if ((int)c < m) {
            int2 p = packed[base + (int)c];
            r = p.x; w = __int_as_float(p.y);
        }
        int rj[8]; float wj[8]; uint4 vj[8];
#pragma unroll
        for (int u = 0; u < 8; ++u) {
            int idx = (u < m) ? u : (m - 1);       // clamp: re-read last valid row
            rj[u] = __shfl(r, idx, 8);
            wj[u] = __shfl(w, u, 8);               // lanes >= m carry w=0
        }
#pragma unroll
        for (int u = 0; u < 8; ++u)
            vj[u] = *(const uint4*)(zin + (size_t)(uint_t)rj[u] * 64u + c * 8u);
#pragma unroll
        for (int u = 0; u < 8; ++u) {
            float ww = wj[u]; uint4 v = vj[u];
            a0.x = fmaf(ww, lo16(v.x), a0.x);
            a0.y = fmaf(ww, hi16(v.x), a0.y);
            a0.z = fmaf(ww, lo16(v.y), a0.z);
            a0.w = fmaf(ww, hi16(v.y), a0.w);
            a1.x = fmaf(ww, lo16(v.z), a1.x);
            a1.y = fmaf(ww, hi16(v.z), a1.y);
            a1.z = fmaf(ww, lo16(v.w), a1.z);
            a1.w = fmaf(ww, hi16(v.w), a1.w);
        }
    }
}

// ---- fused dinv + z0 (8 lanes per node) -------------------------------------
__global__ void dinv_init_kernel(const int2* __restrict__ packed,
                                 const int* __restrict__ offs,
                                 const float* __restrict__ user_w,
                                 const float* __restrict__ audio,
                                 const float* __restrict__ artist_w,
                                 const float* __restrict__ album_w,
                                 const int* __restrict__ artist_ids,
                                 const int* __restrict__ album_ids,
                                 float* __restrict__ dinv,
                                 ushort_t* __restrict__ z0) {
    unsigned t = blockIdx.x * 256u + threadIdx.x;
    unsigned node = t >> 3, c = t & 7u;
    if (node >= NN) return;
    int beg = offs[node], end = offs[node + 1];
    float ds = 0.f;
    for (int k = beg + (int)c; k < end; k += 8) ds += __int_as_float(packed[k].y);
    ds += __shfl_xor(ds, 1, 8);
    ds += __shfl_xor(ds, 2, 8);
    ds += __shfl_xor(ds, 4, 8);
    float d = (ds > 0.f) ? rsqrtf(ds) : 0.f;
    if (c == 0) dinv[node] = d;

    size_t ri = (size_t)node * 64u + c * 8u;
    float v[8];
    if (node < NUM_USERS) {
        float4 x0 = *(const float4*)(user_w + ri);
        float4 x1 = *(const float4*)(user_w + ri + 4);
        v[0]=x0.x; v[1]=x0.y; v[2]=x0.z; v[3]=x0.w;
        v[4]=x1.x; v[5]=x1.y; v[6]=x1.z; v[7]=x1.w;
    } else {
        unsigned j = node - NUM_USERS;
        unsigned aid = (unsigned)artist_ids[j], bid = (unsigned)album_ids[j];
        const float* ap = artist_w + (size_t)aid * 64u + c * 8u;
        const float* bp = album_w  + (size_t)bid * 64u + c * 8u;
        const float* up = audio    + (size_t)j   * 64u + c * 8u;
        float4 A0 = *(const float4*)ap, A1 = *(const float4*)(ap + 4);
        float4 B0 = *(const float4*)bp, B1 = *(const float4*)(bp + 4);
        float4 U0 = *(const float4*)up, U1 = *(const float4*)(up + 4);
        v[0] = fmaf(0.44f, A0.x + B0.x, 0.3f * U0.x);
        v[1] = fmaf(0.44f, A0.y + B0.y, 0.3f * U0.y);
        v[2] = fmaf(0.44f, A0.z + B0.z, 0.3f * U0.z);
        v[3] = fmaf(0.44f, A0.w + B0.w, 0.3f * U0.w);
        v[4] = fmaf(0.44f, A1.x + B1.x, 0.3f * U1.x);
        v[5] = fmaf(0.44f, A1.y + B1.y, 0.3f * U1.y);
        v[6] = fmaf(0.44f, A1.z + B1.z, 0.3f * U1.z);
        v[7] = fmaf(0.44f, A1.w + B1.w, 0.3f * U1.w);
    }
    float s = 0.f;
#pragma unroll
    for (int k = 0; k < 8; ++k) s = fmaf(v[k], v[k], s);
    s += __shfl_xor(s, 1, 8);
    s += __shfl_xor(s, 2, 8);
    s += __shfl_xor(s, 4, 8);
    float rn = rsqrtf(fmaxf(s, 1e-24f));          // == 1/max(||x||,1e-12)
    float scale = ((d > 0.f) ? d : 1.f) * rn;
    uint4 o;
    o.x = pack2(v[0] * scale, v[1] * scale);
    o.y = pack2(v[2] * scale, v[3] * scale);
    o.z = pack2(v[4] * scale, v[5] * scale);
    o.w = pack2(v[6] * scale, v[7] * scale);
    *(uint4*)(z0 + ri) = o;
}

// ---- SpMM layer in z-space: zout[n] = dinv_n^2 * sum ew * zin[row] ----------
__global__ void spmm_kernel(const ushort_t* __restrict__ zin,
                            const int2* __restrict__ packed,
                            const int* __restrict__ offs,
                            const float* __restrict__ dinv,
                            ushort_t* __restrict__ zout) {
    unsigned t = blockIdx.x * 256u + threadIdx.x;
    unsigned node = t >> 3, c = t & 7u;
    if (node >= NN) return;
    float4 a0 = make_float4(0,0,0,0), a1 = make_float4(0,0,0,0);
    gather_node8(zin, packed, offs[node], offs[node + 1], c, a0, a1);
    float d = dinv[node], dd = d * d;
    uint4 o;
    o.x = pack2(a0.x * dd, a0.y * dd);
    o.y = pack2(a0.z * dd, a0.w * dd);
    o.z = pack2(a1.x * dd, a1.y * dd);
    o.w = pack2(a1.z * dd, a1.w * dd);
    *(uint4*)(zout + (size_t)node * 64u + c * 8u) = o;
}

// ---- final layer fused with l2norm: out = l2norm((z0+z1+z2+z3)/4) -----------
__global__ void spmm_final_kernel(const ushort_t* __restrict__ z0,
                                  const ushort_t* __restrict__ z1,
                                  const ushort_t* __restrict__ z2,
                                  const int2* __restrict__ packed,
                                  const int* __restrict__ offs,
                                  const float* __restrict__ dinv,
                                  float* __restrict__ out) {
    unsigned t = blockIdx.x * 256u + threadIdx.x;
    unsigned node = t >> 3, c = t & 7u;
    if (node >= NN) return;
    float4 a0 = make_float4(0,0,0,0), a1 = make_float4(0,0,0,0);
    gather_node8(z2, packed, offs[node], offs[node + 1], c, a0, a1);
    float d = dinv[node], dd = d * d;
    size_t ri = (size_t)node * 64u + c * 8u;
    uint4 p0 = *(const uint4*)(z0 + ri);
    uint4 p1 = *(const uint4*)(z1 + ri);
    uint4 p2 = *(const uint4*)(z2 + ri);
    float v[8];
    v[0] = lo16(p0.x) + lo16(p1.x) + lo16(p2.x) + a0.x * dd;
    v[1] = hi16(p0.x) + hi16(p1.x) + hi16(p2.x) + a0.y * dd;
    v[2] = lo16(p0.y) + lo16(p1.y) + lo16(p2.y) + a0.z * dd;
    v[3] = hi16(p0.y) + hi16(p1.y) + hi16(p2.y) + a0.w * dd;
    v[4] = lo16(p0.z) + lo16(p1.z) + lo16(p2.z) + a1.x * dd;
    v[5] = hi16(p0.z) + hi16(p1.z) + hi16(p2.z) + a1.y * dd;
    v[6] = lo16(p0.w) + lo16(p1.w) + lo16(p2.w) + a1.z * dd;
    v[7] = hi16(p0.w) + hi16(p1.w) + hi16(p2.w) + a1.w * dd;
    float s = 0.f;
#pragma unroll
    for (int k = 0; k < 8; ++k) s = fmaf(v[k], v[k], s);
    s += __shfl_xor(s, 1, 8);
    s += __shfl_xor(s, 2, 8);
    s += __shfl_xor(s, 4, 8);
    float n = fmaxf(sqrtf(s) * 0.25f, 1e-12f);    // norm of acc/4, ref eps
    float inv = 0.25f / n;
    float4 o0 = make_float4(v[0]*inv, v[1]*inv, v[2]*inv, v[3]*inv);
    float4 o1 = make_float4(v[4]*inv, v[5]*inv, v[6]*inv, v[7]*inv);
    *(float4*)(out + ri)     = o0;
    *(float4*)(out + ri + 4) = o1;
    if (t == 0) out[(size_t)NN * 64u] = 0.f;      // align_loss
}

extern "C" void kernel_launch(void* const* d_in, const int* in_sizes, int n_in,
                              void* d_out, int out_size, void* d_ws, size_t ws_size,
                              hipStream_t stream) {
    const float* user_w     = (const float*)d_in[0];
    const float* audio      = (const float*)d_in[1];
    const float* artist_w   = (const float*)d_in[2];
    const float* album_w    = (const float*)d_in[3];
    const float* w1         = (const float*)d_in[4];
    const float* b1         = (const float*)d_in[5];
    const float* w2         = (const float*)d_in[6];
    const float* b2         = (const float*)d_in[7];
    const float* feats      = (const float*)d_in[8];
    const int*   row        = (const int*)d_in[9];
    const int*   col        = row + EE;
    const int*   artist_ids = (const int*)d_in[10];
    const int*   album_ids  = (const int*)d_in[11];
    float* out = (float*)d_out;

    // workspace (4B units): counts[NNP] offs[NNP+16] partials[1024]
    //                        er[EE int2] dinv[NN] packed[EE int2] z0..z2 ~79MB
    int*      counts   = (int*)d_ws;
    int*      offs     = counts + NNP;
    int*      partials = offs + NNP + 16;
    int2*     er       = (int2*)(partials + 1024);
    float*    dinv     = (float*)(er + EE);
    int2*     packed   = (int2*)(dinv + NN);
    ushort_t* z0       = (ushort_t*)(packed + EE);
    ushort_t* z1       = z0 + (size_t)NN * 64;
    ushort_t* z2       = z1 + (size_t)NN * 64;

    hipMemsetAsync(counts, 0, NNP * sizeof(int), stream);

    mlp_count_kernel<<<(EE + 255) / 256, 256, 0, stream>>>(feats, w1, b1, w2, b2,
                                                           col, er, counts);
    scan1_kernel<<<NB, 256, 0, stream>>>(counts, offs, partials);
    scan23_kernel<<<NB, 256, 0, stream>>>(offs, partials);
    fill_kernel<<<(EE + 255) / 256, 256, 0, stream>>>(er, row, col, offs, packed);
    dinv_init_kernel<<<G8_BLOCKS, 256, 0, stream>>>(packed, offs,
                                                    user_w, audio, artist_w, album_w,
                                                    artist_ids, album_ids, dinv, z0);
    spmm_kernel<<<G8_BLOCKS, 256, 0, stream>>>(z0, packed, offs, dinv, z1);
    spmm_kernel<<<G8_BLOCKS, 256, 0, stream>>>(z1, packed, offs, dinv, z2);
    spmm_final_kernel<<<G8_BLOCKS, 256, 0, stream>>>(z0, z1, z2, packed, offs,
                                                     dinv, out);
}

// Round 3
// 300.327 us; speedup vs baseline: 2.3044x; 1.0653x over previous
//
#include <hip/hip_runtime.h>
#include <math.h>

#define NUM_USERS 100000
#define NUM_ITEMS 50000
#define NN 150000               // total nodes
#define EE 1200000              // total directed edges (2 * E_DIR)
#define NNP 150016              // padded node count = 293*512
#define G8_BLOCKS 4688          // ceil(NN*8/256) for 8-lane-per-node kernels

// CSR-build (bucket sort) parameters
#define NBUCKET 293             // ceil(NNP/512); NBUCKET*512 == NNP exactly
#define NB2 256                 // blocks for hist/scatter1
#define EPB 4688                // edges per block = ceil(EE/NB2) -> 256*4688 >= EE

typedef unsigned short ushort_t;
typedef unsigned int uint_t;

__device__ __forceinline__ uint_t pack2(float lo, float hi) {   // 2x fp32 -> bf16x2 RNE
    uint_t a = __float_as_uint(lo);
    uint_t b = __float_as_uint(hi);
    a = (a + 0x7FFFu + ((a >> 16) & 1u)) >> 16;
    b = (b + 0x7FFFu + ((b >> 16) & 1u)) & 0xFFFF0000u;
    return a | b;
}
__device__ __forceinline__ float lo16(uint_t x) { return __uint_as_float(x << 16); }
__device__ __forceinline__ float hi16(uint_t x) { return __uint_as_float(x & 0xFFFF0000u); }

// ---- edge MLP only: w[e] = sigmoid(mlp(feats[e])).  NO atomics. -------------
__global__ void mlp_kernel(const float* __restrict__ feats,
                           const float* __restrict__ w1,
                           const float* __restrict__ b1,
                           const float* __restrict__ w2,
                           const float* __restrict__ b2,
                           float* __restrict__ wout) {
    __shared__ float sw1t[256];      // transposed: sw1t[j*8+i] = w1[i][j]
    __shared__ float2 shb[32];       // {b1[j], w2[j]}
    __shared__ float sb2s;
    int t = threadIdx.x;
    sw1t[t] = w1[(t & 7) * 32 + (t >> 3)];
    if (t < 32) shb[t] = make_float2(b1[t], w2[t]);
    if (t == 0) sb2s = b2[0];
    __syncthreads();
    int e = blockIdx.x * 256 + t;
    if (e >= EE) return;
    const float4* fp = (const float4*)(feats + (size_t)e * 8);
    float4 fa = fp[0], fb = fp[1];
    float f[8] = {fa.x, fa.y, fa.z, fa.w, fb.x, fb.y, fb.z, fb.w};
    float s = sb2s;
#pragma unroll
    for (int j = 0; j < 32; ++j) {
        float4 wa = *(const float4*)&sw1t[j * 8];
        float4 wb = *(const float4*)&sw1t[j * 8 + 4];
        float2 bw = shb[j];
        float h = bw.x;
        h = fmaf(f[0], wa.x, h);
        h = fmaf(f[1], wa.y, h);
        h = fmaf(f[2], wa.z, h);
        h = fmaf(f[3], wa.w, h);
        h = fmaf(f[4], wb.x, h);
        h = fmaf(f[5], wb.y, h);
        h = fmaf(f[6], wb.z, h);
        h = fmaf(f[7], wb.w, h);
        h = fmaxf(h, 0.f);
        s = fmaf(h, bw.y, s);
    }
    wout[e] = 1.f / (1.f + expf(-s));
}

// ---- K2: per-block bucket histogram (bucket = col>>9), LDS atomics only -----
__global__ void hist_kernel(const int* __restrict__ col,
                            int* __restrict__ hist) {      // hist[NBUCKET*NB2]
    __shared__ int h[NBUCKET];
    int t = threadIdx.x, B = blockIdx.x;
    for (int i = t; i < NBUCKET; i += 256) h[i] = 0;
    __syncthreads();
    int beg = B * EPB, end = beg + EPB; if (end > EE) end = EE;
    for (int i = beg + t; i < end; i += 256)
        atomicAdd(&h[col[i] >> 9], 1);                     // LDS atomic
    __syncthreads();
    for (int i = t; i < NBUCKET; i += 256) hist[i * NB2 + B] = h[i];
}

// ---- K3: per-bucket exclusive scan over its 256 block-counts (in place) -----
__global__ void scanb_kernel(int* __restrict__ hist,       // [NBUCKET][NB2]
                             int* __restrict__ tot) {      // [NBUCKET]
    int b = blockIdx.x, t = threadIdx.x;
    int v = hist[b * NB2 + t];
    int lane = t & 63;
    int s = v;
#pragma unroll
    for (int off = 1; off < 64; off <<= 1) {
        int u = __shfl_up(s, off, 64);
        if (lane >= off) s += u;
    }
    __shared__ int wsum[4];
    if (lane == 63) wsum[t >> 6] = s;
    __syncthreads();
    int add = 0;
    for (int w = 0; w < (t >> 6); ++w) add += wsum[w];
    hist[b * NB2 + t] = s - v + add;                       // exclusive prefix
    if (t == 255) tot[b] = s + add;                        // bucket total
}

// ---- K3b: scan bucket totals -> bucket base offsets (single block) ----------
__global__ void scant_kernel(const int* __restrict__ tot,
                             int* __restrict__ base) {     // base[NBUCKET+1]
    int t = threadIdx.x;                                   // 512 threads
    int v = (t < NBUCKET) ? tot[t] : 0;
    int lane = t & 63;
    int s = v;
#pragma unroll
    for (int off = 1; off < 64; off <<= 1) {
        int u = __shfl_up(s, off, 64);
        if (lane >= off) s += u;
    }
    __shared__ int wsum[8];
    if (lane == 63) wsum[t >> 6] = s;
    __syncthreads();
    int add = 0;
    for (int w = 0; w < (t >> 6); ++w) add += wsum[w];
    if (t < NBUCKET) base[t] = s - v + add;                // exclusive
    if (t == 511) base[NBUCKET] = s + add;                 // == EE
}

// ---- K4: scatter edges into bucket-major tmp records (L2-local runs) --------
__global__ void scatter1_kernel(const int* __restrict__ col,
                                const int* __restrict__ row,
                                const float* __restrict__ wbuf,
                                const int* __restrict__ hist,   // scanned
                                const int* __restrict__ base,
                                int4* __restrict__ tmp) {
    __shared__ int bbase[NBUCKET];
    __shared__ int cur[NBUCKET];
    int t = threadIdx.x, B = blockIdx.x;
    for (int i = t; i < NBUCKET; i += 256) {
        bbase[i] = base[i] + hist[i * NB2 + B];
        cur[i] = 0;
    }
    __syncthreads();
    int beg = B * EPB, end = beg + EPB; if (end > EE) end = EE;
    for (int i = beg + t; i < end; i += 256) {
        int c = col[i];
        int b = c >> 9;
        int r = atomicAdd(&cur[b], 1);                     // LDS returning atomic
        tmp[bbase[b] + r] = make_int4(c, row[i], __float_as_int(wbuf[i]), 0);
    }
}

// ---- K5: within-bucket exact-col sort -> packed + offs (one block/bucket) ---
__global__ void scatter2_kernel(const int4* __restrict__ tmp,
                                const int* __restrict__ base,
                                int* __restrict__ offs,
                                int2* __restrict__ packed) {
    __shared__ int sc[512];                                // count -> scan -> cursor
    __shared__ int wsum[8];
    int b = blockIdx.x, t = threadIdx.x;                   // 512 threads
    int beg = base[b], end = base[b + 1];
    sc[t] = 0;
    __syncthreads();
    for (int i = beg + t; i < end; i += 512)
        atomicAdd(&sc[tmp[i].x & 511], 1);                 // per-col count (LDS)
    __syncthreads();
    int v = sc[t];
    int lane = t & 63;
    int s = v;
#pragma unroll
    for (int off = 1; off < 64; off <<= 1) {
        int u = __shfl_up(s, off, 64);
        if (lane >= off) s += u;
    }
    if (lane == 63) wsum[t >> 6] = s;
    __syncthreads();
    int add = 0;
    for (int w = 0; w < (t >> 6); ++w) add += wsum[w];
    int excl = s - v + add;
    offs[b * 512 + t] = beg + excl;                        // global CSR offset
    __syncthreads();
    sc[t] = excl;                                          // becomes cursor
    __syncthreads();
    for (int i = beg + t; i < end; i += 512) {
        int4 rec = tmp[i];
        int r = atomicAdd(&sc[rec.x & 511], 1);            // within-bucket slot
        packed[beg + r] = make_int2(rec.y, rec.z);
    }
}

// ---- gather core: 8 lanes per node, 16B loads; a0/a1 = cols 8c..8c+7 --------
__device__ __forceinline__ void gather_node8(const ushort_t* __restrict__ zin,
                                             const int2* __restrict__ packed,
                                             int beg, int end, unsigned c,
                                             float4& a0, float4& a1) {
    for (int base = beg; base < end; base += 8) {
        int m = end - base; if (m > 8) m = 8;
        int r = 0; float w = 0.f;
        if ((int)c < m) {
            int2 p = packed[base + (int)c];
            r = p.x; w = __int_as_float(p.y);
        }
        int rj[8]; float wj[8]; uint4 vj[8];
#pragma unroll
        for (int u = 0; u < 8; ++u) {
            int idx = (u < m) ? u : (m - 1);       // clamp: re-read last valid row
            rj[u] = __shfl(r, idx, 8);
            wj[u] = __shfl(w, u, 8);               // lanes >= m carry w=0
        }
#pragma unroll
        for (int u = 0; u < 8; ++u)
            vj[u] = *(const uint4*)(zin + (size_t)(uint_t)rj[u] * 64u + c * 8u);
#pragma unroll
        for (int u = 0; u < 8; ++u) {
            float ww = wj[u]; uint4 v = vj[u];
            a0.x = fmaf(ww, lo16(v.x), a0.x);
            a0.y = fmaf(ww, hi16(v.x), a0.y);
            a0.z = fmaf(ww, lo16(v.y), a0.z);
            a0.w = fmaf(ww, hi16(v.y), a0.w);
            a1.x = fmaf(ww, lo16(v.z), a1.x);
            a1.y = fmaf(ww, hi16(v.z), a1.y);
            a1.z = fmaf(ww, lo16(v.w), a1.z);
            a1.w = fmaf(ww, hi16(v.w), a1.w);
        }
    }
}

// ---- fused dinv + z0 (8 lanes per node) -------------------------------------
__global__ void dinv_init_kernel(const int2* __restrict__ packed,
                                 const int* __restrict__ offs,
                                 const float* __restrict__ user_w,
                                 const float* __restrict__ audio,
                                 const float* __restrict__ artist_w,
                                 const float* __restrict__ album_w,
                                 const int* __restrict__ artist_ids,
                                 const int* __restrict__ album_ids,
                                 float* __restrict__ dinv,
                                 ushort_t* __restrict__ z0) {
    unsigned t = blockIdx.x * 256u + threadIdx.x;
    unsigned node = t >> 3, c = t & 7u;
    if (node >= NN) return;
    int beg = offs[node], end = offs[node + 1];
    float ds = 0.f;
    for (int k = beg + (int)c; k < end; k += 8) ds += __int_as_float(packed[k].y);
    ds += __shfl_xor(ds, 1, 8);
    ds += __shfl_xor(ds, 2, 8);
    ds += __shfl_xor(ds, 4, 8);
    float d = (ds > 0.f) ? rsqrtf(ds) : 0.f;
    if (c == 0) dinv[node] = d;

    size_t ri = (size_t)node * 64u + c * 8u;
    float v[8];
    if (node < NUM_USERS) {
        float4 x0 = *(const float4*)(user_w + ri);
        float4 x1 = *(const float4*)(user_w + ri + 4);
        v[0]=x0.x; v[1]=x0.y; v[2]=x0.z; v[3]=x0.w;
        v[4]=x1.x; v[5]=x1.y; v[6]=x1.z; v[7]=x1.w;
    } else {
        unsigned j = node - NUM_USERS;
        unsigned aid = (unsigned)artist_ids[j], bid = (unsigned)album_ids[j];
        const float* ap = artist_w + (size_t)aid * 64u + c * 8u;
        const float* bp = album_w  + (size_t)bid * 64u + c * 8u;
        const float* up = audio    + (size_t)j   * 64u + c * 8u;
        float4 A0 = *(const float4*)ap, A1 = *(const float4*)(ap + 4);
        float4 B0 = *(const float4*)bp, B1 = *(const float4*)(bp + 4);
        float4 U0 = *(const float4*)up, U1 = *(const float4*)(up + 4);
        v[0] = fmaf(0.44f, A0.x + B0.x, 0.3f * U0.x);
        v[1] = fmaf(0.44f, A0.y + B0.y, 0.3f * U0.y);
        v[2] = fmaf(0.44f, A0.z + B0.z, 0.3f * U0.z);
        v[3] = fmaf(0.44f, A0.w + B0.w, 0.3f * U0.w);
        v[4] = fmaf(0.44f, A1.x + B1.x, 0.3f * U1.x);
        v[5] = fmaf(0.44f, A1.y + B1.y, 0.3f * U1.y);
        v[6] = fmaf(0.44f, A1.z + B1.z, 0.3f * U1.z);
        v[7] = fmaf(0.44f, A1.w + B1.w, 0.3f * U1.w);
    }
    float s = 0.f;
#pragma unroll
    for (int k = 0; k < 8; ++k) s = fmaf(v[k], v[k], s);
    s += __shfl_xor(s, 1, 8);
    s += __shfl_xor(s, 2, 8);
    s += __shfl_xor(s, 4, 8);
    float rn = rsqrtf(fmaxf(s, 1e-24f));          // == 1/max(||x||,1e-12)
    float scale = ((d > 0.f) ? d : 1.f) * rn;
    uint4 o;
    o.x = pack2(v[0] * scale, v[1] * scale);
    o.y = pack2(v[2] * scale, v[3] * scale);
    o.z = pack2(v[4] * scale, v[5] * scale);
    o.w = pack2(v[6] * scale, v[7] * scale);
    *(uint4*)(z0 + ri) = o;
}

// ---- SpMM layer in z-space: zout[n] = dinv_n^2 * sum ew * zin[row] ----------
__global__ void spmm_kernel(const ushort_t* __restrict__ zin,
                            const int2* __restrict__ packed,
                            const int* __restrict__ offs,
                            const float* __restrict__ dinv,
                            ushort_t* __restrict__ zout) {
    unsigned t = blockIdx.x * 256u + threadIdx.x;
    unsigned node = t >> 3, c = t & 7u;
    if (node >= NN) return;
    float4 a0 = make_float4(0,0,0,0), a1 = make_float4(0,0,0,0);
    gather_node8(zin, packed, offs[node], offs[node + 1], c, a0, a1);
    float d = dinv[node], dd = d * d;
    uint4 o;
    o.x = pack2(a0.x * dd, a0.y * dd);
    o.y = pack2(a0.z * dd, a0.w * dd);
    o.z = pack2(a1.x * dd, a1.y * dd);
    o.w = pack2(a1.z * dd, a1.w * dd);
    *(uint4*)(zout + (size_t)node * 64u + c * 8u) = o;
}

// ---- final layer fused with l2norm: out = l2norm((z0+z1+z2+z3)/4) -----------
__global__ void spmm_final_kernel(const ushort_t* __restrict__ z0,
                                  const ushort_t* __restrict__ z1,
                                  const ushort_t* __restrict__ z2,
                                  const int2* __restrict__ packed,
                                  const int* __restrict__ offs,
                                  const float* __restrict__ dinv,
                                  float* __restrict__ out) {
    unsigned t = blockIdx.x * 256u + threadIdx.x;
    unsigned node = t >> 3, c = t & 7u;
    if (node >= NN) return;
    float4 a0 = make_float4(0,0,0,0), a1 = make_float4(0,0,0,0);
    gather_node8(z2, packed, offs[node], offs[node + 1], c, a0, a1);
    float d = dinv[node], dd = d * d;
    size_t ri = (size_t)node * 64u + c * 8u;
    uint4 p0 = *(const uint4*)(z0 + ri);
    uint4 p1 = *(const uint4*)(z1 + ri);
    uint4 p2 = *(const uint4*)(z2 + ri);
    float v[8];
    v[0] = lo16(p0.x) + lo16(p1.x) + lo16(p2.x) + a0.x * dd;
    v[1] = hi16(p0.x) + hi16(p1.x) + hi16(p2.x) + a0.y * dd;
    v[2] = lo16(p0.y) + lo16(p1.y) + lo16(p2.y) + a0.z * dd;
    v[3] = hi16(p0.y) + hi16(p1.y) + hi16(p2.y) + a0.w * dd;
    v[4] = lo16(p0.z) + lo16(p1.z) + lo16(p2.z) + a1.x * dd;
    v[5] = hi16(p0.z) + hi16(p1.z) + hi16(p2.z) + a1.y * dd;
    v[6] = lo16(p0.w) + lo16(p1.w) + lo16(p2.w) + a1.z * dd;
    v[7] = hi16(p0.w) + hi16(p1.w) + hi16(p2.w) + a1.w * dd;
    float s = 0.f;
#pragma unroll
    for (int k = 0; k < 8; ++k) s = fmaf(v[k], v[k], s);
    s += __shfl_xor(s, 1, 8);
    s += __shfl_xor(s, 2, 8);
    s += __shfl_xor(s, 4, 8);
    float n = fmaxf(sqrtf(s) * 0.25f, 1e-12f);    // norm of acc/4, ref eps
    float inv = 0.25f / n;
    float4 o0 = make_float4(v[0]*inv, v[1]*inv, v[2]*inv, v[3]*inv);
    float4 o1 = make_float4(v[4]*inv, v[5]*inv, v[6]*inv, v[7]*inv);
    *(float4*)(out + ri)     = o0;
    *(float4*)(out + ri + 4) = o1;
    if (t == 0) out[(size_t)NN * 64u] = 0.f;      // align_loss
}

extern "C" void kernel_launch(void* const* d_in, const int* in_sizes, int n_in,
                              void* d_out, int out_size, void* d_ws, size_t ws_size,
                              hipStream_t stream) {
    const float* user_w     = (const float*)d_in[0];
    const float* audio      = (const float*)d_in[1];
    const float* artist_w   = (const float*)d_in[2];
    const float* album_w    = (const float*)d_in[3];
    const float* w1         = (const float*)d_in[4];
    const float* b1         = (const float*)d_in[5];
    const float* w2         = (const float*)d_in[6];
    const float* b2         = (const float*)d_in[7];
    const float* feats      = (const float*)d_in[8];
    const int*   row        = (const int*)d_in[9];
    const int*   col        = row + EE;
    const int*   artist_ids = (const int*)d_in[10];
    const int*   album_ids  = (const int*)d_in[11];
    float* out = (float*)d_out;

    // workspace (4B units):
    //   hist[NBUCKET*NB2] tot[512] base[512] offs[NNP+16]
    //   wbuf[EE] dinv[NN] packed[EE int2] z0 z1 z2 (bf16 rows)
    //   tmp (int4[EE], 19.2MB) aliased onto z1 (dead before spmm #1 writes z1)
    int*      hist    = (int*)d_ws;
    int*      tot     = hist + NBUCKET * NB2;
    int*      base    = tot + 512;
    int*      offs    = base + 512;
    float*    wbuf    = (float*)(offs + NNP + 16);
    float*    dinv    = wbuf + EE;
    int2*     packed  = (int2*)(dinv + NN);
    ushort_t* z0      = (ushort_t*)(packed + EE);
    ushort_t* z1      = z0 + (size_t)NN * 64;
    ushort_t* z2      = z1 + (size_t)NN * 64;
    int4*     tmp     = (int4*)z1;

    mlp_kernel<<<(EE + 255) / 256, 256, 0, stream>>>(feats, w1, b1, w2, b2, wbuf);
    hist_kernel<<<NB2, 256, 0, stream>>>(col, hist);
    scanb_kernel<<<NBUCKET, 256, 0, stream>>>(hist, tot);
    scant_kernel<<<1, 512, 0, stream>>>(tot, base);
    scatter1_kernel<<<NB2, 256, 0, stream>>>(col, row, wbuf, hist, base, tmp);
    scatter2_kernel<<<NBUCKET, 512, 0, stream>>>(tmp, base, offs, packed);
    dinv_init_kernel<<<G8_BLOCKS, 256, 0, stream>>>(packed, offs,
                                                    user_w, audio, artist_w, album_w,
                                                    artist_ids, album_ids, dinv, z0);
    spmm_kernel<<<G8_BLOCKS, 256, 0, stream>>>(z0, packed, offs, dinv, z1);
    spmm_kernel<<<G8_BLOCKS, 256, 0, stream>>>(z1, packed, offs, dinv, z2);
    spmm_final_kernel<<<G8_BLOCKS, 256, 0, stream>>>(z0, z1, z2, packed, offs,
                                                     dinv, out);
}